// Round 8
// baseline (201.492 us; speedup 1.0000x reference)
//
#include <hip/hip_runtime.h>
#include <math.h>

namespace {
constexpr int B_ = 32, S_ = 1024, D_ = 256, N_ = 32, C_ = 64;
constexpr int NC_ = N_ * C_;  // 2048
constexpr int XP_ = 16;       // s-chunks per b

typedef __bf16 bf16x8 __attribute__((ext_vector_type(8)));
typedef __bf16 bf16x4 __attribute__((ext_vector_type(4)));
typedef float floatx4 __attribute__((ext_vector_type(4)));

constexpr int XS_ = 264;  // x_lds row stride
constexpr int TS_ = 264;  // t_lds row stride
constexpr int CS_ = 72;   // c_T row stride (s 64 + 8 pad)
}  // namespace

// K1: per (b, s-chunk): xsum partials (column sums over 64 s-rows).
extern "C" __global__ __launch_bounds__(256) void k_stage(
    const float* __restrict__ x, float* __restrict__ xsum_part) {
  const int b = blockIdx.x, sb = blockIdx.y, t = threadIdx.x;
  const float* xb = x + ((size_t)b * S_ + sb * 64) * D_;
  float a = 0.f;
  #pragma unroll 8
  for (int s = 0; s < 64; ++s) a += xb[s * D_ + t];
  xsum_part[((size_t)b * XP_ + sb) * D_ + t] = a;
}

// K2 (small chain) per (b,n):
//   zloc[d] = sum_p z[...]  (P partials)
//   s[c] = scale * zloc@W[n];  v = squash(s)
//   final: write v to vout;  else: t = W[n]@v (+= old t if accum) -> fp32 + bf16 hi/lo
extern "C" __global__ __launch_bounds__(256) void k_small(
    const float* __restrict__ z, const float* __restrict__ W,
    float* __restrict__ t_fp, __bf16* __restrict__ t_bhi,
    __bf16* __restrict__ t_blo, float* __restrict__ vout,
    int P, int zb, int zp, int zn, float scale, int accum, int final_) {
  __shared__ float zloc[256];
  __shared__ float sq_red[4][64];
  __shared__ float v_lds[64];
  const int b = blockIdx.x, n = blockIdx.y, t = threadIdx.x;

  float a = 0.f;
  for (int p = 0; p < P; ++p) a += z[(size_t)b * zb + (size_t)p * zp + n * zn + t];
  zloc[t] = a;
  __syncthreads();

  const int c = t & 63, dq = t >> 6;
  const float* Wn = W + (size_t)n * (D_ * C_);
  float s = 0.f;
  #pragma unroll 8
  for (int dd = 0; dd < 64; ++dd) {
    int d = dq * 64 + dd;
    s += zloc[d] * Wn[d * 64 + c];
  }
  sq_red[dq][c] = s;
  __syncthreads();

  if (t < 64) {
    float sc = (sq_red[0][t] + sq_red[1][t] + sq_red[2][t] + sq_red[3][t]) * scale;
    float sq = sc * sc;
    #pragma unroll
    for (int m = 1; m <= 32; m <<= 1) sq += __shfl_xor(sq, m);
    float scl = sq / ((1.f + sq) * sqrtf(sq + 1e-8f));
    float v = sc * scl;
    v_lds[t] = v;
    if (final_) vout[(size_t)b * NC_ + n * 64 + t] = v;
  }
  __syncthreads();

  if (!final_) {
    const float4* W4 = (const float4*)Wn + t * 16;
    float acc = 0.f;
    #pragma unroll
    for (int q = 0; q < 16; ++q) {
      float4 wv = W4[q];
      acc += wv.x * v_lds[q * 4] + wv.y * v_lds[q * 4 + 1] +
             wv.z * v_lds[q * 4 + 2] + wv.w * v_lds[q * 4 + 3];
    }
    size_t idx = ((size_t)b * N_ + n) * D_ + t;
    float tf = acc + (accum ? t_fp[idx] : 0.f);
    t_fp[idx] = tf;
    __bf16 hi = (__bf16)tf;
    t_bhi[idx] = hi;
    t_blo[idx] = (__bf16)(tf - (float)hi);
  }
}

// K3 (routing pass) per (b, s-chunk of 64):
//   stage x fp32 -> bf16 LDS + t hi/lo -> LDS; agr[s,n] = x.t via MFMA ->
//   softmax over n -> y_part[ch] = c^T @ x via MFMA, plain coalesced stores
//   (each block owns its private partial slice -- no atomics, no y zeroing).
extern "C" __global__ __launch_bounds__(256) void k_pass(
    const float* __restrict__ x, const __bf16* __restrict__ t_bhi,
    const __bf16* __restrict__ t_blo, float* __restrict__ y_part) {
  __shared__ __align__(16) __bf16 x_lds[64 * XS_];
  __shared__ __align__(16) __bf16 th_lds[N_ * TS_];
  __shared__ __align__(16) __bf16 tl_lds[N_ * TS_];
  __shared__ __align__(16) __bf16 c_Th[N_ * CS_];
  __shared__ __align__(16) __bf16 c_Tl[N_ * CS_];
  const int b = blockIdx.x, ch = blockIdx.y;
  const int t = threadIdx.x, w = t >> 6, lane = t & 63;
  const int quad = lane >> 4, l16 = lane & 15;

  // stage t hi/lo (8192 bf16 each, per b)
  #pragma unroll
  for (int e = 0; e < 4; ++e) {
    int idx = e * 2048 + t * 8;
    int n = idx >> 8, d = idx & 255;
    *(uint4*)(th_lds + n * TS_ + d) = *(const uint4*)(t_bhi + (size_t)b * 8192 + idx);
    *(uint4*)(tl_lds + n * TS_ + d) = *(const uint4*)(t_blo + (size_t)b * 8192 + idx);
  }
  // stage x chunk: fp32 global -> bf16 LDS (same rounding as before)
  const float* xsrc = x + ((size_t)b * S_ + ch * 64) * D_;
  #pragma unroll
  for (int e = 0; e < 16; ++e) {
    int idx = e * 1024 + t * 4;
    int row = idx >> 8, col = idx & 255;
    float4 f = *(const float4*)(xsrc + idx);
    bf16x4 p4;
    p4[0] = (__bf16)f.x; p4[1] = (__bf16)f.y;
    p4[2] = (__bf16)f.z; p4[3] = (__bf16)f.w;
    *(bf16x4*)(x_lds + row * XS_ + col) = p4;
  }
  __syncthreads();

  // agreement GEMM: A=t (m=n), B=x (n'=s), K=256; wave w owns s-tile w*16
  floatx4 acc[2];
  acc[0] = (floatx4){0.f, 0.f, 0.f, 0.f};
  acc[1] = (floatx4){0.f, 0.f, 0.f, 0.f};
  const int sbase = w * 16;
  #pragma unroll
  for (int k0 = 0; k0 < 256; k0 += 32) {
    int ks = k0 + quad * 8;
    bf16x8 bfrag = *(const bf16x8*)(x_lds + (sbase + l16) * XS_ + ks);
    #pragma unroll
    for (int i = 0; i < 2; ++i) {
      bf16x8 ah = *(const bf16x8*)(th_lds + (i * 16 + l16) * TS_ + ks);
      bf16x8 al = *(const bf16x8*)(tl_lds + (i * 16 + l16) * TS_ + ks);
      acc[i] = __builtin_amdgcn_mfma_f32_16x16x32_bf16(ah, bfrag, acc[i], 0, 0, 0);
      acc[i] = __builtin_amdgcn_mfma_f32_16x16x32_bf16(al, bfrag, acc[i], 0, 0, 0);
    }
  }
  // softmax over n for s = sbase + l16
  float mx = -1e30f;
  #pragma unroll
  for (int i = 0; i < 2; ++i)
    #pragma unroll
    for (int r = 0; r < 4; ++r) mx = fmaxf(mx, acc[i][r]);
  mx = fmaxf(mx, __shfl_xor(mx, 16));
  mx = fmaxf(mx, __shfl_xor(mx, 32));
  float e_[2][4];
  float ss = 0.f;
  #pragma unroll
  for (int i = 0; i < 2; ++i)
    #pragma unroll
    for (int r = 0; r < 4; ++r) { e_[i][r] = __expf(acc[i][r] - mx); ss += e_[i][r]; }
  ss += __shfl_xor(ss, 16);
  ss += __shfl_xor(ss, 32);
  float inv = 1.f / ss;
  #pragma unroll
  for (int i = 0; i < 2; ++i)
    #pragma unroll
    for (int r = 0; r < 4; ++r) {
      float cv = e_[i][r] * inv;
      __bf16 chi = (__bf16)cv;
      int o = (i * 16 + quad * 4 + r) * CS_ + sbase + l16;
      c_Th[o] = chi;
      c_Tl[o] = (__bf16)(cv - (float)chi);
    }
  __syncthreads();

  // y GEMM: y_part[n,d] = c^T @ x; wave w owns d-range w*64
  floatx4 acc2[2][4];
  #pragma unroll
  for (int i = 0; i < 2; ++i)
    #pragma unroll
    for (int dt = 0; dt < 4; ++dt) acc2[i][dt] = (floatx4){0.f, 0.f, 0.f, 0.f};
  const int dbase = w * 64;
  #pragma unroll
  for (int k0 = 0; k0 < 64; k0 += 32) {
    int ks = k0 + quad * 8;
    bf16x8 ah[2], al[2];
    #pragma unroll
    for (int i = 0; i < 2; ++i) {
      ah[i] = *(const bf16x8*)(c_Th + (i * 16 + l16) * CS_ + ks);
      al[i] = *(const bf16x8*)(c_Tl + (i * 16 + l16) * CS_ + ks);
    }
    #pragma unroll
    for (int dt = 0; dt < 4; ++dt) {
      bf16x8 bfr;
      #pragma unroll
      for (int j8 = 0; j8 < 8; ++j8)
        bfr[j8] = x_lds[(ks + j8) * XS_ + dbase + dt * 16 + l16];
      #pragma unroll
      for (int i = 0; i < 2; ++i) {
        acc2[i][dt] = __builtin_amdgcn_mfma_f32_16x16x32_bf16(ah[i], bfr, acc2[i][dt], 0, 0, 0);
        acc2[i][dt] = __builtin_amdgcn_mfma_f32_16x16x32_bf16(al[i], bfr, acc2[i][dt], 0, 0, 0);
      }
    }
  }
  // private partial slice: plain coalesced stores, no atomics
  float* yo = y_part + ((size_t)(b * XP_ + ch) * N_) * D_;
  #pragma unroll
  for (int i = 0; i < 2; ++i)
    #pragma unroll
    for (int dt = 0; dt < 4; ++dt)
      #pragma unroll
      for (int r = 0; r < 4; ++r) {
        int n = i * 16 + quad * 4 + r;
        int d = dbase + dt * 16 + l16;
        yo[n * D_ + d] = acc2[i][dt][r];
      }
}

extern "C" void kernel_launch(void* const* d_in, const int* in_sizes, int n_in,
                              void* d_out, int out_size, void* d_ws, size_t ws_size,
                              hipStream_t stream) {
  const float* x = (const float*)d_in[0];   // [B,S,D] fp32
  const float* W = (const float*)d_in[1];   // [N,D,C] fp32
  float* out = (float*)d_out;               // [B,N,C] fp32

  // ws (~18.5 MB): [xsum_part 512K | y_part 16.78M | t_fp 1M | t_bhi 512K | t_blo 512K]
  char* ws = (char*)d_ws;
  float* xsum_part = (float*)ws;                       // [B,XP,D]
  float* y_part = (float*)(ws + 524288);               // [B,XP,N,D]
  float* t_fp = (float*)(ws + 524288 + 16777216);      // [B,N,D]
  __bf16* t_bhi = (__bf16*)(t_fp + B_ * N_ * D_);      // [B,N,D]
  __bf16* t_blo = t_bhi + B_ * N_ * D_;                // [B,N,D]

  // 1) xsum partials
  k_stage<<<dim3(B_, XP_), 256, 0, stream>>>(x, xsum_part);

  // 2) iter 0: s1=(1/N)xsum@W -> v1 -> t1
  k_small<<<dim3(B_, N_), 256, 0, stream>>>(
      xsum_part, W, t_fp, t_bhi, t_blo, nullptr,
      XP_, XP_ * D_, D_, 0, 1.f / 32.f, 0, 0);

  // 3) pass 1 -- MEASUREMENT: launched 3x (idempotent, bit-identical output;
  //    extra dispatches isolate k_pass duration: T ~= 159 + 4*(k_pass+gap))
  k_pass<<<dim3(B_, XP_), 256, 0, stream>>>(x, t_bhi, t_blo, y_part);
  k_pass<<<dim3(B_, XP_), 256, 0, stream>>>(x, t_bhi, t_blo, y_part);
  k_pass<<<dim3(B_, XP_), 256, 0, stream>>>(x, t_bhi, t_blo, y_part);

  // 4) s2=sum_ch y_part@W -> v2 -> t12 = t1 + W@v2
  k_small<<<dim3(B_, N_), 256, 0, stream>>>(
      y_part, W, t_fp, t_bhi, t_blo, nullptr,
      XP_, XP_ * N_ * D_, N_ * D_, D_, 1.f, 1, 0);

  // 5) pass 2 -- also 3x (idempotent)
  k_pass<<<dim3(B_, XP_), 256, 0, stream>>>(x, t_bhi, t_blo, y_part);
  k_pass<<<dim3(B_, XP_), 256, 0, stream>>>(x, t_bhi, t_blo, y_part);
  k_pass<<<dim3(B_, XP_), 256, 0, stream>>>(x, t_bhi, t_blo, y_part);

  // 6) s3=sum_ch y_part@W -> squash -> out
  k_small<<<dim3(B_, N_), 256, 0, stream>>>(
      y_part, W, t_fp, t_bhi, t_blo, out,
      XP_, XP_ * N_ * D_, N_ * D_, D_, 1.f, 0, 1);
}

// Round 10
// 164.011 us; speedup vs baseline: 1.2285x; 1.2285x over previous
//
#include <hip/hip_runtime.h>
#include <math.h>

namespace {
constexpr int B_ = 32, S_ = 1024, D_ = 256, N_ = 32, C_ = 64;
constexpr int NC_ = N_ * C_;  // 2048
constexpr int XP_ = 16;       // s-chunks per b
constexpr int BPG_ = 4;       // batches per k_small block
constexpr int GB_ = B_ / BPG_;  // 8 batch-groups

typedef __bf16 bf16x8 __attribute__((ext_vector_type(8)));
typedef __bf16 bf16x4 __attribute__((ext_vector_type(4)));
typedef float floatx4 __attribute__((ext_vector_type(4)));

constexpr int XS_ = 264;  // x_lds row stride
constexpr int TS_ = 264;  // t_lds row stride
constexpr int CS_ = 72;   // c_T row stride (s 64 + 8 pad)
}  // namespace

// K1: per (b, s-chunk): xsum partials (column sums over 64 s-rows).
extern "C" __global__ __launch_bounds__(256) void k_stage(
    const float* __restrict__ x, float* __restrict__ xsum_part) {
  const int b = blockIdx.x, sb = blockIdx.y, t = threadIdx.x;
  const float* xb = x + ((size_t)b * S_ + sb * 64) * D_;
  float a = 0.f;
  #pragma unroll 8
  for (int s = 0; s < 64; ++s) a += xb[s * D_ + t];
  xsum_part[((size_t)b * XP_ + sb) * D_ + t] = a;
}

// K2 (small chain) per (n, batch-group of 4):
//   For each of 4 b's: zloc[d] = sum_p z[...]; s[c] = scale*zloc@W[n];
//   v = squash(s); final: v -> vout; else t = W[n]@v (+= old) -> fp32 + hi/lo.
//   W values are loaded ONCE per block and applied to all 4 b's (register
//   reuse; zloc/v broadcast from LDS) -- 4x less W traffic than per-(b,n).
//   Per-(b,n) arithmetic chains identical to the verified per-block version.
extern "C" __global__ __launch_bounds__(256) void k_small(
    const float* __restrict__ z, const float* __restrict__ W,
    float* __restrict__ t_fp, __bf16* __restrict__ t_bhi,
    __bf16* __restrict__ t_blo, float* __restrict__ vout,
    int P, int zb, int zp, int zn, float scale, int accum, int final_) {
  __shared__ float zloc[BPG_][256];
  __shared__ float sq_red[BPG_][4][64];
  __shared__ float v_lds[BPG_][64];
  const int n = blockIdx.x, bg = blockIdx.y, t = threadIdx.x;
  const int b0 = bg * BPG_;
  const int c = t & 63, dq = t >> 6;

  #pragma unroll
  for (int bb = 0; bb < BPG_; ++bb) {
    const float* zsrc = z + (size_t)(b0 + bb) * zb + n * zn + t;
    float a = 0.f;
    for (int p = 0; p < P; ++p) a += zsrc[(size_t)p * zp];
    zloc[bb][t] = a;
  }
  __syncthreads();

  const float* Wn = W + (size_t)n * (D_ * C_);
  float s[BPG_] = {0.f, 0.f, 0.f, 0.f};
  #pragma unroll 8
  for (int dd = 0; dd < 64; ++dd) {
    int d = dq * 64 + dd;
    float wv = Wn[d * 64 + c];
    #pragma unroll
    for (int bb = 0; bb < BPG_; ++bb) s[bb] += zloc[bb][d] * wv;
  }
  #pragma unroll
  for (int bb = 0; bb < BPG_; ++bb) sq_red[bb][dq][c] = s[bb];
  __syncthreads();

  {
    const int bb = t >> 6;  // wave w handles batch b0+w; lanes = c
    float sc = (sq_red[bb][0][c] + sq_red[bb][1][c] + sq_red[bb][2][c] +
                sq_red[bb][3][c]) * scale;
    float sq = sc * sc;
    #pragma unroll
    for (int m = 1; m <= 32; m <<= 1) sq += __shfl_xor(sq, m);
    float scl = sq / ((1.f + sq) * sqrtf(sq + 1e-8f));
    float v = sc * scl;
    v_lds[bb][c] = v;
    if (final_) vout[(size_t)(b0 + bb) * NC_ + n * 64 + c] = v;
  }
  __syncthreads();

  if (!final_) {
    const float4* W4 = (const float4*)Wn + t * 16;
    float acc[BPG_] = {0.f, 0.f, 0.f, 0.f};
    #pragma unroll
    for (int q = 0; q < 16; ++q) {
      float4 wv = W4[q];
      #pragma unroll
      for (int bb = 0; bb < BPG_; ++bb) {
        const float* vb = &v_lds[bb][q * 4];
        acc[bb] += wv.x * vb[0] + wv.y * vb[1] + wv.z * vb[2] + wv.w * vb[3];
      }
    }
    #pragma unroll
    for (int bb = 0; bb < BPG_; ++bb) {
      size_t idx = ((size_t)(b0 + bb) * N_ + n) * D_ + t;
      float tf = acc[bb] + (accum ? t_fp[idx] : 0.f);
      t_fp[idx] = tf;
      __bf16 hi = (__bf16)tf;
      t_bhi[idx] = hi;
      t_blo[idx] = (__bf16)(tf - (float)hi);
    }
  }
}

// K3 (routing pass) per (b, s-chunk of 64):
//   stage x fp32 -> bf16 LDS + t hi/lo -> LDS; agr[s,n] = x.t via MFMA ->
//   softmax over n -> y_part[ch] = c^T @ x via MFMA, plain coalesced stores
//   (each block owns its private partial slice -- no atomics, no y zeroing).
extern "C" __global__ __launch_bounds__(256) void k_pass(
    const float* __restrict__ x, const __bf16* __restrict__ t_bhi,
    const __bf16* __restrict__ t_blo, float* __restrict__ y_part) {
  __shared__ __align__(16) __bf16 x_lds[64 * XS_];
  __shared__ __align__(16) __bf16 th_lds[N_ * TS_];
  __shared__ __align__(16) __bf16 tl_lds[N_ * TS_];
  __shared__ __align__(16) __bf16 c_Th[N_ * CS_];
  __shared__ __align__(16) __bf16 c_Tl[N_ * CS_];
  const int b = blockIdx.x, ch = blockIdx.y;
  const int t = threadIdx.x, w = t >> 6, lane = t & 63;
  const int quad = lane >> 4, l16 = lane & 15;

  // stage t hi/lo (8192 bf16 each, per b)
  #pragma unroll
  for (int e = 0; e < 4; ++e) {
    int idx = e * 2048 + t * 8;
    int n = idx >> 8, d = idx & 255;
    *(uint4*)(th_lds + n * TS_ + d) = *(const uint4*)(t_bhi + (size_t)b * 8192 + idx);
    *(uint4*)(tl_lds + n * TS_ + d) = *(const uint4*)(t_blo + (size_t)b * 8192 + idx);
  }
  // stage x chunk: fp32 global -> bf16 LDS (same rounding as before)
  const float* xsrc = x + ((size_t)b * S_ + ch * 64) * D_;
  #pragma unroll
  for (int e = 0; e < 16; ++e) {
    int idx = e * 1024 + t * 4;
    int row = idx >> 8, col = idx & 255;
    float4 f = *(const float4*)(xsrc + idx);
    bf16x4 p4;
    p4[0] = (__bf16)f.x; p4[1] = (__bf16)f.y;
    p4[2] = (__bf16)f.z; p4[3] = (__bf16)f.w;
    *(bf16x4*)(x_lds + row * XS_ + col) = p4;
  }
  __syncthreads();

  // agreement GEMM: A=t (m=n), B=x (n'=s), K=256; wave w owns s-tile w*16
  floatx4 acc[2];
  acc[0] = (floatx4){0.f, 0.f, 0.f, 0.f};
  acc[1] = (floatx4){0.f, 0.f, 0.f, 0.f};
  const int sbase = w * 16;
  #pragma unroll
  for (int k0 = 0; k0 < 256; k0 += 32) {
    int ks = k0 + quad * 8;
    bf16x8 bfrag = *(const bf16x8*)(x_lds + (sbase + l16) * XS_ + ks);
    #pragma unroll
    for (int i = 0; i < 2; ++i) {
      bf16x8 ah = *(const bf16x8*)(th_lds + (i * 16 + l16) * TS_ + ks);
      bf16x8 al = *(const bf16x8*)(tl_lds + (i * 16 + l16) * TS_ + ks);
      acc[i] = __builtin_amdgcn_mfma_f32_16x16x32_bf16(ah, bfrag, acc[i], 0, 0, 0);
      acc[i] = __builtin_amdgcn_mfma_f32_16x16x32_bf16(al, bfrag, acc[i], 0, 0, 0);
    }
  }
  // softmax over n for s = sbase + l16
  float mx = -1e30f;
  #pragma unroll
  for (int i = 0; i < 2; ++i)
    #pragma unroll
    for (int r = 0; r < 4; ++r) mx = fmaxf(mx, acc[i][r]);
  mx = fmaxf(mx, __shfl_xor(mx, 16));
  mx = fmaxf(mx, __shfl_xor(mx, 32));
  float e_[2][4];
  float ss = 0.f;
  #pragma unroll
  for (int i = 0; i < 2; ++i)
    #pragma unroll
    for (int r = 0; r < 4; ++r) { e_[i][r] = __expf(acc[i][r] - mx); ss += e_[i][r]; }
  ss += __shfl_xor(ss, 16);
  ss += __shfl_xor(ss, 32);
  float inv = 1.f / ss;
  #pragma unroll
  for (int i = 0; i < 2; ++i)
    #pragma unroll
    for (int r = 0; r < 4; ++r) {
      float cv = e_[i][r] * inv;
      __bf16 chi = (__bf16)cv;
      int o = (i * 16 + quad * 4 + r) * CS_ + sbase + l16;
      c_Th[o] = chi;
      c_Tl[o] = (__bf16)(cv - (float)chi);
    }
  __syncthreads();

  // y GEMM: y_part[n,d] = c^T @ x; wave w owns d-range w*64
  floatx4 acc2[2][4];
  #pragma unroll
  for (int i = 0; i < 2; ++i)
    #pragma unroll
    for (int dt = 0; dt < 4; ++dt) acc2[i][dt] = (floatx4){0.f, 0.f, 0.f, 0.f};
  const int dbase = w * 64;
  #pragma unroll
  for (int k0 = 0; k0 < 64; k0 += 32) {
    int ks = k0 + quad * 8;
    bf16x8 ah[2], al[2];
    #pragma unroll
    for (int i = 0; i < 2; ++i) {
      ah[i] = *(const bf16x8*)(c_Th + (i * 16 + l16) * CS_ + ks);
      al[i] = *(const bf16x8*)(c_Tl + (i * 16 + l16) * CS_ + ks);
    }
    #pragma unroll
    for (int dt = 0; dt < 4; ++dt) {
      bf16x8 bfr;
      #pragma unroll
      for (int j8 = 0; j8 < 8; ++j8)
        bfr[j8] = x_lds[(ks + j8) * XS_ + dbase + dt * 16 + l16];
      #pragma unroll
      for (int i = 0; i < 2; ++i) {
        acc2[i][dt] = __builtin_amdgcn_mfma_f32_16x16x32_bf16(ah[i], bfr, acc2[i][dt], 0, 0, 0);
        acc2[i][dt] = __builtin_amdgcn_mfma_f32_16x16x32_bf16(al[i], bfr, acc2[i][dt], 0, 0, 0);
      }
    }
  }
  // private partial slice: plain coalesced stores, no atomics
  float* yo = y_part + ((size_t)(b * XP_ + ch) * N_) * D_;
  #pragma unroll
  for (int i = 0; i < 2; ++i)
    #pragma unroll
    for (int dt = 0; dt < 4; ++dt)
      #pragma unroll
      for (int r = 0; r < 4; ++r) {
        int n = i * 16 + quad * 4 + r;
        int d = dbase + dt * 16 + l16;
        yo[n * D_ + d] = acc2[i][dt][r];
      }
}

extern "C" void kernel_launch(void* const* d_in, const int* in_sizes, int n_in,
                              void* d_out, int out_size, void* d_ws, size_t ws_size,
                              hipStream_t stream) {
  const float* x = (const float*)d_in[0];   // [B,S,D] fp32
  const float* W = (const float*)d_in[1];   // [N,D,C] fp32
  float* out = (float*)d_out;               // [B,N,C] fp32

  // ws (~18.5 MB): [xsum_part 512K | y_part 16.78M | t_fp 1M | t_bhi 512K | t_blo 512K]
  char* ws = (char*)d_ws;
  float* xsum_part = (float*)ws;                       // [B,XP,D]
  float* y_part = (float*)(ws + 524288);               // [B,XP,N,D]
  float* t_fp = (float*)(ws + 524288 + 16777216);      // [B,N,D]
  __bf16* t_bhi = (__bf16*)(t_fp + B_ * N_ * D_);      // [B,N,D]
  __bf16* t_blo = t_bhi + B_ * N_ * D_;                // [B,N,D]

  // 1) xsum partials
  k_stage<<<dim3(B_, XP_), 256, 0, stream>>>(x, xsum_part);

  // 2) iter 0: s1=(1/N)xsum@W -> v1 -> t1
  k_small<<<dim3(N_, GB_), 256, 0, stream>>>(
      xsum_part, W, t_fp, t_bhi, t_blo, nullptr,
      XP_, XP_ * D_, D_, 0, 1.f / 32.f, 0, 0);

  // 3) pass 1: y_part[ch] = c2^T @ x(chunk ch)
  k_pass<<<dim3(B_, XP_), 256, 0, stream>>>(x, t_bhi, t_blo, y_part);

  // 4) s2=sum_ch y_part@W -> v2 -> t12 = t1 + W@v2
  k_small<<<dim3(N_, GB_), 256, 0, stream>>>(
      y_part, W, t_fp, t_bhi, t_blo, nullptr,
      XP_, XP_ * N_ * D_, N_ * D_, D_, 1.f, 1, 0);

  // 5) pass 2: y_part[ch] = c3^T @ x(chunk ch)
  k_pass<<<dim3(B_, XP_), 256, 0, stream>>>(x, t_bhi, t_blo, y_part);

  // 6) s3=sum_ch y_part@W -> squash -> out
  k_small<<<dim3(N_, GB_), 256, 0, stream>>>(
      y_part, W, t_fp, t_bhi, t_blo, out,
      XP_, XP_ * N_ * D_, N_ * D_, D_, 1.f, 0, 1);
}